// Round 14
// baseline (184.597 us; speedup 1.0000x reference)
//
#include <hip/hip_runtime.h>
#include <math.h>

#define Tt 250
#define TnN 243
#define Nn 256
#define EPS_ 1e-5f
#define LOG2E 1.44269504f

typedef unsigned short u16;
typedef __bf16 bf16x8 __attribute__((ext_vector_type(8)));
typedef __bf16 bf16x4 __attribute__((ext_vector_type(4)));
typedef float f32x4 __attribute__((ext_vector_type(4)));

__device__ __forceinline__ u16 f2bf(float f) {
    unsigned u = __builtin_bit_cast(unsigned, f);
    u += 0x7FFFu + ((u >> 16) & 1u);
    return (u16)(u >> 16);
}
__device__ __forceinline__ float bf2f(u16 s) {
    unsigned u = ((unsigned)s) << 16;
    return __builtin_bit_cast(float, u);
}
__device__ __forceinline__ float hw_exp2(float x) {
    return __builtin_amdgcn_exp2f(x);
}

__device__ __forceinline__ void async_load16(const void* g, void* l) {
    __builtin_amdgcn_global_load_lds(
        (const __attribute__((address_space(1))) unsigned int*)g,
        (__attribute__((address_space(3))) unsigned int*)l, 16, 0, 0);
}

// generalized padded-row DMA: LDS rows of 72 u16 (64 valid + 8 pad), global rows of rstride u16.
__device__ __forceinline__ void dma72g(const u16* gsrc, int rstride, u16* ldst, int nseg,
                                       int w, int lane, int nw) {
    for (int seg = w; seg < nseg; seg += nw) {
        int c9 = seg * 64 + lane;
        int row = c9 / 9, sub = c9 - row * 9;
        const u16* src = (sub < 8) ? &gsrc[row * rstride + sub * 8] : gsrc;
        async_load16(src, ldst + seg * 512);
    }
}

// serial c-chain over one transposed row pair (row stride 252), direction D compile-time.
template<int D>
__device__ __forceinline__ void chain_run(u16* Zr, u16* Fr, float kf, float bf_) {
    bf16x8 z8 = *(const bf16x8*)&Zr[D ? 240 : 0];
    bf16x8 f8 = *(const bf16x8*)&Fr[D ? 240 : 0];
    float c = 0.f;
    for (int grp = 0; grp < 31; ++grp) {
        int gb = D ? (30 - grp) * 8 : grp * 8;
        bf16x8 zn = z8, fn = f8;
        if (grp < 30) {
            int gbn = D ? (29 - grp) * 8 : (grp + 1) * 8;
            zn = *(const bf16x8*)&Zr[gbn];
            fn = *(const bf16x8*)&Fr[gbn];
        }
        bf16x8 co;
        #pragma unroll
        for (int k = 0; k < 8; ++k) {
            const int idx = D ? (7 - k) : k;
            int t = gb + idx;
            float uz = (float)z8[idx];
            float af = -LOG2E * ((float)f8[idx] + bf_);
            float xe = fmaf(kf, c, af);
            float fg = __builtin_amdgcn_rcpf(1.f + hw_exp2(xe));
            float cn = fmaf(fg, c - uz, uz);
            bool ok = (t < TnN);
            if (ok) c = cn;
            co[idx] = ok ? (__bf16)c : (__bf16)0.f;
        }
        *(bf16x8*)&Zr[gb] = co;
        z8 = zn; f8 = fn;
    }
}

// ---------------- fused stats + normalize + transpose + weight packing ----------------
// 256 blocks x 512 threads (1/CU -> all co-resident at launch; no dispatch-order dependence
// beyond co-residency of a grid <= CU count). Each block:
//   1) partial (sum,sumsq) over ITS OWN x-slice [b, :, f, :] -> AGENT-scope store + counter
//   2) weight packing (independent) hides other blocks' partial latency
//   3) spin on counter (AGENT-scope), reduce 128 partials, normalize from L2-hot slice
__global__ __launch_bounds__(512) void k_norm(const float* __restrict__ x,
                       const float* __restrict__ gamma, const float* __restrict__ beta,
                       const float* __restrict__ W0, const float* __restrict__ Wr,
                       const float* __restrict__ wct,
                       float* __restrict__ stats, unsigned* __restrict__ cnt,
                       u16* __restrict__ xbt, u16* __restrict__ W0k,
                       u16* __restrict__ Wrt, u16* __restrict__ Wcto) {
    __shared__ u16 lt[64 * 260];
    __shared__ float ls[8], ls2[8], sm2[2];
    const int n = blockIdx.x, tid = threadIdx.x;
    const int b = n >> 7, f = n & 127;
    const int c = tid >> 3, vq = tid & 7;
    const float* xr = x + ((size_t)(b * 64 + c) * 128 + f) * Tt;

    // --- phase 1: partial sums over this block's slice (the slice we normalize later)
    {
        float s = 0.f, s2 = 0.f;
        #pragma unroll
        for (int j = 0; j < 16; ++j) {
            int t0 = vq * 2 + j * 16;        // even t, 0..254
            if (t0 < Tt) {
                float2 xv = *(const float2*)&xr[t0];
                s  += xv.x + xv.y;
                s2 += xv.x * xv.x + xv.y * xv.y;
            }
        }
        for (int off = 32; off; off >>= 1) {
            s  += __shfl_down(s, off);
            s2 += __shfl_down(s2, off);
        }
        int lane = tid & 63, w = tid >> 6;
        if (lane == 0) { ls[w] = s; ls2[w] = s2; }
        __syncthreads();
        if (tid == 0) {
            float a = 0.f, a2 = 0.f;
            for (int i = 0; i < 8; i++) { a += ls[i]; a2 += ls2[i]; }
            __hip_atomic_store(&stats[n * 2],     a,  __ATOMIC_RELAXED, __HIP_MEMORY_SCOPE_AGENT);
            __hip_atomic_store(&stats[n * 2 + 1], a2, __ATOMIC_RELAXED, __HIP_MEMORY_SCOPE_AGENT);
            __hip_atomic_fetch_add(&cnt[b], 1u, __ATOMIC_RELEASE, __HIP_MEMORY_SCOPE_AGENT);
        }
    }

    // --- phase 2: weight packing (independent of stats) hides the wait
    #pragma unroll
    for (int it = 0; it < 2; ++it) {
        int idx = it * 131072 + n * 512 + tid;
        if (idx < 131072) {
            int k = idx >> 14, j = (idx >> 6) & 255, cc = idx & 63;
            int d = j >> 7, ck = cc * 8 + k;
            W0k[idx] = f2bf(W0[((size_t)d * 512 + ck) * 128 + (j & 127)]);
        } else if (idx < 180224) {
            int r = idx - 131072;
            int i = r & 63, j = (r >> 6) & 255, lidx = r >> 14;
            Wrt[r] = f2bf(Wr[(size_t)(lidx * 2 + (j >> 7)) * 8192 + i * 128 + (j & 127)]);
        } else if (idx < 212992) {
            int r = idx - 180224;
            int o = r >> 9; int k = r & 511; int kk = k >> 6, ci = k & 63;
            Wcto[r] = f2bf(wct[(size_t)ci * 512 + o * 8 + kk]);
        }
    }

    // --- phase 3: wait for all 128 partials of this batch, reduce
    if (tid == 0) {
        while (__hip_atomic_load(&cnt[b], __ATOMIC_ACQUIRE, __HIP_MEMORY_SCOPE_AGENT) < 128u) {}
    }
    __syncthreads();
    if (tid < 64) {
        float a = 0.f, a2 = 0.f;
        #pragma unroll
        for (int p = 0; p < 2; ++p) {
            int sb = b * 128 + tid + p * 64;
            a  += __hip_atomic_load(&stats[sb * 2],     __ATOMIC_RELAXED, __HIP_MEMORY_SCOPE_AGENT);
            a2 += __hip_atomic_load(&stats[sb * 2 + 1], __ATOMIC_RELAXED, __HIP_MEMORY_SCOPE_AGENT);
        }
        for (int off = 32; off; off >>= 1) {
            a  += __shfl_down(a, off);
            a2 += __shfl_down(a2, off);
        }
        if (tid == 0) { sm2[0] = a; sm2[1] = a2; }
    }
    __syncthreads();

    // --- phase 4: normalize (slice is L2-hot from phase 1) + transpose
    const float inv = 1.0f / (float)(64 * 128 * Tt);
    float mean = sm2[0] * inv;
    float var  = sm2[1] * inv - mean * mean;
    float rstd = rsqrtf(var + EPS_);
    const float gm = gamma[c] * rstd;
    const float bt = beta[c] - mean * gm;
    #pragma unroll
    for (int j = 0; j < 16; ++j) {
        int t0 = vq * 2 + j * 16;
        unsigned pv = 0u;
        if (t0 < Tt) {
            float2 xv = *(const float2*)&xr[t0];
            pv = (unsigned)f2bf(fmaf(xv.x, gm, bt)) | ((unsigned)f2bf(fmaf(xv.y, gm, bt)) << 16);
        }
        *(unsigned*)&lt[c * 260 + t0] = pv;
    }
    __syncthreads();
    const int cg = tid & 7, tq = tid >> 3;
    #pragma unroll
    for (int it = 0; it < 4; ++it) {
        int t = it * 64 + tq;
        u16 tmp[8];
        #pragma unroll
        for (int jj = 0; jj < 8; ++jj) tmp[jj] = lt[(cg * 8 + jj) * 260 + t];
        uint4 o;
        o.x = (unsigned)tmp[0] | ((unsigned)tmp[1] << 16);
        o.y = (unsigned)tmp[2] | ((unsigned)tmp[3] << 16);
        o.z = (unsigned)tmp[4] | ((unsigned)tmp[5] << 16);
        o.w = (unsigned)tmp[6] | ((unsigned)tmp[7] << 16);
        *(uint4*)&xbt[(size_t)n * 16384 + t * 64 + cg * 8] = o;
    }
}

// ---------------- mega tail (1024 threads / 16 waves, 8M x 2N wave tiling) ----------------
// LDS map (u16): Hs 0..19007 (264x72), ZT 19008 (64x252), FT 35136 (64x252), Bm 51264 (256x72).
#define HS0 0
#define ZT0 19008
#define FT0 35136
#define BM0 51264
#define SH_U16 81856
__global__ __launch_bounds__(1024) void k_tail(const u16* __restrict__ XbT,
                                               const u16* __restrict__ W0k,
                                               const u16* __restrict__ Wrt,
                                               const u16* __restrict__ Wc,
                                               const float* __restrict__ v,
                                               const float* __restrict__ bbias,
                                               const float* __restrict__ bct,
                                               const float* __restrict__ x,
                                               float* __restrict__ out) {
    __shared__ __align__(16) u16 sh[SH_U16];
    u16* Hs = sh + HS0;
    u16* ZT = sh + ZT0;
    u16* FT = sh + FT0;
    u16* Bm = sh + BM0;
    const int tid = threadIdx.x;
    const int n = blockIdx.x;
    const int lane = tid & 63, w = tid >> 6;          // w in 0..15
    const int ml = lane & 15, q = lane >> 4;
    const int wm = w >> 1, wn = w & 1;                // M-tile index / N-half (= direction)
    const int b = n >> 7, f = n & 127;

    for (int lay = 0; lay < 4; ++lay) {
        f32x4 acc[2][8];
        #pragma unroll
        for (int mt = 0; mt < 2; ++mt)
            #pragma unroll
            for (int nt = 0; nt < 8; ++nt) acc[mt][nt] = (f32x4){0.f, 0.f, 0.f, 0.f};

        if (lay == 0) {
            const u16* Xn = XbT + (size_t)n * 16384;
            u16* Bb0 = sh + ZT0;                       // dead ZT/FT span
            u16* Bb1 = Bm;
            dma72g(Xn, 64, Hs, 36, w, lane, 16);       // A tile rows 0..255
            dma72g(W0k, 64, Bb0, 36, w, lane, 16);     // B k=0
            __syncthreads();
            #pragma unroll
            for (int k = 0; k < 8; ++k) {
                u16* Bl = (k & 1) ? Bb1 : Bb0;
                if (k < 7)
                    dma72g(W0k + (size_t)(k + 1) * 16384, 64, (k & 1) ? Bb0 : Bb1, 36, w, lane, 16);
                #pragma unroll
                for (int c2 = 0; c2 < 2; ++c2) {
                    int c0 = c2 * 32;
                    bf16x8 af[2];
                    #pragma unroll
                    for (int mt = 0; mt < 2; ++mt)
                        af[mt] = *(const bf16x8*)&Hs[(wm * 32 + mt * 16 + ml + k) * 72 + c0 + q * 8];
                    #pragma unroll
                    for (int nt = 0; nt < 8; ++nt) {
                        bf16x8 bfr = *(const bf16x8*)&Bl[(wn * 128 + nt * 16 + ml) * 72 + c0 + q * 8];
                        #pragma unroll
                        for (int mt = 0; mt < 2; ++mt)
                            acc[mt][nt] = __builtin_amdgcn_mfma_f32_16x16x32_bf16(af[mt], bfr, acc[mt][nt], 0, 0, 0);
                    }
                }
                __syncthreads();
            }
        } else {
            #pragma unroll
            for (int c2 = 0; c2 < 2; ++c2) {
                int c0 = c2 * 32;
                bf16x8 af[2];
                #pragma unroll
                for (int mt = 0; mt < 2; ++mt)
                    af[mt] = *(const bf16x8*)&Hs[(wm * 32 + mt * 16 + ml + 7) * 72 + c0 + q * 8];
                #pragma unroll
                for (int nt = 0; nt < 8; ++nt) {
                    bf16x8 bfr = *(const bf16x8*)&Bm[(wn * 128 + nt * 16 + ml) * 72 + c0 + q * 8];
                    #pragma unroll
                    for (int mt = 0; mt < 2; ++mt)
                        acc[mt][nt] = __builtin_amdgcn_mfma_f32_16x16x32_bf16(af[mt], bfr, acc[mt][nt], 0, 0, 0);
                }
            }
        }

        // epi: z/f preacts (nt 0..3) -> ZT/FT rows (wn*32+hh); r/x (nt 4..7) stay in registers
        #pragma unroll
        for (int mt = 0; mt < 2; ++mt) {
            int t0 = wm * 32 + mt * 16 + q * 4;
            if (t0 < TnN) {
                bool vec = (t0 + 4 <= TnN);
                #pragma unroll
                for (int nt = 0; nt < 4; ++nt) {
                    int g2 = nt >> 1, hh = (nt & 1) * 16 + ml;
                    u16* P = (g2 ? FT : ZT) + (wn * 32 + hh) * 252;
                    if (vec) {
                        uint2 pv;
                        pv.x = (unsigned)f2bf(acc[mt][nt][0]) | ((unsigned)f2bf(acc[mt][nt][1]) << 16);
                        pv.y = (unsigned)f2bf(acc[mt][nt][2]) | ((unsigned)f2bf(acc[mt][nt][3]) << 16);
                        *(uint2*)&P[t0] = pv;
                    } else {
                        #pragma unroll
                        for (int r = 0; r < 4; ++r) {
                            int t = t0 + r;
                            if (t < TnN) P[t] = f2bf(acc[mt][nt][r]);
                        }
                    }
                }
            }
        }
        __syncthreads();

        // next-B DMA hidden under the serial chain
        if (lay < 3) {
            dma72g(Wrt + (size_t)lay * 16384, 64, Bm, 36, w, lane, 16);
        } else {
            #pragma unroll
            for (int i = 0; i < 4; ++i)
                dma72g(Wc + i * 64, 512, Bm + i * 4608, 9, w, lane, 16);
        }

        const float* vv = v + (size_t)(lay * 2) * 64;
        const float* bv = bbias + (size_t)(lay * 2) * 64;

        if (w < 2 && lane < 32) {
            const int d = w, h = lane;
            const float vf = vv[d * 64 + h], bf_ = bv[d * 64 + h];
            const float kf = -LOG2E * vf;
            u16* Zr = &ZT[(d * 32 + h) * 252];
            u16* Fr = &FT[(d * 32 + h) * 252];
            if (d == 0) chain_run<0>(Zr, Fr, kf, bf_);
            else        chain_run<1>(Zr, Fr, kf, bf_);
        }
        __syncthreads();

        if (lay == 0) {
            for (int i = tid; i < 21 * 72; i += 1024) {
                int r = i / 72, ci = i - r * 72;
                int row = r < 7 ? r : (TnN + r);
                Hs[row * 72 + ci] = 0;
            }
        }
        // h-phase: d2 = wn; r/x preacts from registers, c via vector LDS reads; writes Hs
        #pragma unroll
        for (int mt = 0; mt < 2; ++mt) {
            int t0 = wm * 32 + mt * 16 + q * 4;
            if (t0 < TnN) {
                #pragma unroll
                for (int hi = 0; hi < 2; ++hi) {
                    int hh = hi * 16 + ml;
                    float vr_ = vv[wn * 64 + 32 + hh], br_ = bv[wn * 64 + 32 + hh];
                    float kr = -LOG2E * vr_;
                    const u16* Cr = &ZT[(wn * 32 + hh) * 252];
                    bf16x4 c4 = *(const bf16x4*)&Cr[t0];
                    float ct[4];
                    #pragma unroll
                    for (int r = 0; r < 4; ++r) ct[r] = (float)c4[r];
                    float cprv[4];
                    if (wn == 0) {
                        cprv[0] = (t0 == 0) ? 0.f : bf2f(Cr[t0 - 1]);
                        cprv[1] = ct[0]; cprv[2] = ct[1]; cprv[3] = ct[2];
                    } else {
                        cprv[0] = ct[1]; cprv[1] = ct[2]; cprv[2] = ct[3];
                        cprv[3] = bf2f(Cr[t0 + 4]);
                    }
                    f32x4 rp = acc[mt][4 + hi];
                    f32x4 xp = acc[mt][6 + hi];
                    #pragma unroll
                    for (int r = 0; r < 4; ++r) {
                        int t = t0 + r;
                        if (t < TnN) {
                            float cpr = cprv[r];
                            if (wn == 1 && t == TnN - 1) cpr = 0.f;
                            float xr = fmaf(kr, cpr, -LOG2E * (rp[r] + br_));
                            float rg = __builtin_amdgcn_rcpf(1.f + hw_exp2(xr));
                            float hv = fmaf(rg, ct[r] - xp[r], xp[r]);
                            Hs[(t + 7) * 72 + wn * 32 + hh] = f2bf(hv);
                        }
                    }
                }
            }
        }
        __syncthreads();
    }

    // ---- conv phase: taps 0..3 pre-staged in Bm; taps 4..7 DMA'd under taps 0..3 ----
    {
        u16* T47 = sh + ZT0;                      // 4 x 4608, ends 37440
        float* Cf = (float*)(sh + 37440);         // fp32 scratch (dead span; barriered vs Bm reads)
        const int tc0 = w * 16 + q * 4;
        f32x4 cacc[4] = {};
        #pragma unroll
        for (int i = 0; i < 4; ++i)
            dma72g(Wc + (4 + i) * 64, 512, T47 + i * 4608, 9, w, lane, 16);
        #pragma unroll
        for (int m = 0; m < 8; ++m) {
            if (m == 4) __syncthreads();
            const u16* Bl = (m < 4) ? (Bm + m * 4608) : (T47 + (m - 4) * 4608);
            #pragma unroll
            for (int c2 = 0; c2 < 2; ++c2) {
                int ci0 = c2 * 32;
                bf16x8 af = *(const bf16x8*)&Hs[(w * 16 + ml - m + 7) * 72 + ci0 + q * 8];
                #pragma unroll
                for (int nt = 0; nt < 4; ++nt) {
                    bf16x8 bfv = *(const bf16x8*)&Bl[(nt * 16 + ml) * 72 + ci0 + q * 8];
                    cacc[nt] = __builtin_amdgcn_mfma_f32_16x16x32_bf16(af, bfv, cacc[nt], 0, 0, 0);
                }
            }
        }
        __syncthreads();
        float bc[4];
        #pragma unroll
        for (int nt = 0; nt < 4; ++nt) bc[nt] = bct[nt * 16 + ml];
        #pragma unroll
        for (int r = 0; r < 4; ++r) {
            int t = tc0 + r;
            if (t < Tt) {
                #pragma unroll
                for (int nt = 0; nt < 4; ++nt)
                    Cf[t * 68 + nt * 16 + ml] = cacc[nt][r] + bc[nt];
            }
        }
        __syncthreads();
        {
            const int sub = tid & 15;
            const int o = tid >> 4;
            const float* xrow = x + ((size_t)(b * 64 + o) * 128 + f) * Tt;
            float* orow = out + ((size_t)(b * 64 + o) * 128 + f) * Tt;
            #pragma unroll
            for (int it = 0; it < 8; ++it) {
                int j = it * 32 + sub * 2;
                if (j < Tt) {
                    float2 xv = *(const float2*)&xrow[j];
                    float2 ov;
                    ov.x = Cf[j * 68 + o] + xv.x;
                    ov.y = Cf[(j + 1) * 68 + o] + xv.y;
                    *(float2*)&orow[j] = ov;
                }
            }
        }
    }
}

extern "C" void kernel_launch(void* const* d_in, const int* in_sizes, int n_in,
                              void* d_out, int out_size, void* d_ws, size_t ws_size,
                              hipStream_t stream) {
    (void)in_sizes; (void)n_in; (void)out_size; (void)ws_size;
    const float* x     = (const float*)d_in[0];
    const float* gamma = (const float*)d_in[1];
    const float* beta  = (const float*)d_in[2];
    const float* W0    = (const float*)d_in[3];
    const float* Wr    = (const float*)d_in[4];
    const float* v     = (const float*)d_in[5];
    const float* bb    = (const float*)d_in[6];
    const float* wct   = (const float*)d_in[7];
    const float* bct   = (const float*)d_in[8];
    float* out = (float*)d_out;

    char* base = (char*)d_ws;
    float* stats = (float*)base;                         // 2048 B: 256 partial (s,s2) pairs
    unsigned* cnt = (unsigned*)(base + 2048);            // 8 B: per-batch arrival counters
    u16* W0k  = (u16*)(base + 4096);                     // 262144 B  [8 k][256 j][64 c]
    u16* Wrt  = (u16*)(base + 4096 + 262144);            // 98304 B
    u16* Wcto = (u16*)(base + 4096 + 262144 + 98304);    // 65536 B
    u16* XbT  = (u16*)(base + 4096 + 262144 + 98304 + 65536);  // 8.39 MB [256 n][256 t][64 c]

    hipMemsetAsync(cnt, 0, 8, stream);
    k_norm<<<dim3(256), 512, 0, stream>>>(x, gamma, beta, W0, Wr, wct,
                                          stats, cnt, XbT, W0k, Wrt, Wcto);
    k_tail<<<dim3(256), 1024, 0, stream>>>(XbT, W0k, Wrt, Wcto, v, bb, bct, x, out);
}

// Round 15
// 168.232 us; speedup vs baseline: 1.0973x; 1.0973x over previous
//
#include <hip/hip_runtime.h>
#include <math.h>

#define Tt 250
#define TnN 243
#define Nn 256
#define EPS_ 1e-5f
#define LOG2E 1.44269504f

typedef unsigned short u16;
typedef __bf16 bf16x8 __attribute__((ext_vector_type(8)));
typedef float f32x4 __attribute__((ext_vector_type(4)));

__device__ __forceinline__ u16 f2bf(float f) {
    unsigned u = __builtin_bit_cast(unsigned, f);
    u += 0x7FFFu + ((u >> 16) & 1u);
    return (u16)(u >> 16);
}
__device__ __forceinline__ float bf2f(u16 s) {
    unsigned u = ((unsigned)s) << 16;
    return __builtin_bit_cast(float, u);
}
__device__ __forceinline__ float hw_exp2(float x) {
    return __builtin_amdgcn_exp2f(x);
}

__device__ __forceinline__ void async_load16(const void* g, void* l) {
    __builtin_amdgcn_global_load_lds(
        (const __attribute__((address_space(1))) unsigned int*)g,
        (__attribute__((address_space(3))) unsigned int*)l, 16, 0, 0);
}

// generalized padded-row DMA: LDS rows of 72 u16 (64 valid + 8 pad), global rows of rstride u16.
__device__ __forceinline__ void dma72g(const u16* gsrc, int rstride, u16* ldst, int nseg,
                                       int w, int lane, int nw) {
    for (int seg = w; seg < nseg; seg += nw) {
        int c9 = seg * 64 + lane;
        int row = c9 / 9, sub = c9 - row * 9;
        const u16* src = (sub < 8) ? &gsrc[row * rstride + sub * 8] : gsrc;
        async_load16(src, ldst + seg * 512);
    }
}

// serial c-chain over one transposed row pair, direction D compile-time.
template<int D>
__device__ __forceinline__ void chain_run(u16* Zr, u16* Fr, float kf, float bf_) {
    bf16x8 z8 = *(const bf16x8*)&Zr[D ? 240 : 0];
    bf16x8 f8 = *(const bf16x8*)&Fr[D ? 240 : 0];
    float c = 0.f;
    for (int grp = 0; grp < 31; ++grp) {
        int gb = D ? (30 - grp) * 8 : grp * 8;
        bf16x8 zn = z8, fn = f8;
        if (grp < 30) {
            int gbn = D ? (29 - grp) * 8 : (grp + 1) * 8;
            zn = *(const bf16x8*)&Zr[gbn];
            fn = *(const bf16x8*)&Fr[gbn];
        }
        bf16x8 co;
        #pragma unroll
        for (int k = 0; k < 8; ++k) {
            const int idx = D ? (7 - k) : k;
            int t = gb + idx;
            float uz = (float)z8[idx];
            float af = -LOG2E * ((float)f8[idx] + bf_);
            float xe = fmaf(kf, c, af);
            float fg = __builtin_amdgcn_rcpf(1.f + hw_exp2(xe));
            float cn = fmaf(fg, c - uz, uz);
            bool ok = (t < TnN);
            if (ok) c = cn;
            co[idx] = ok ? (__bf16)c : (__bf16)0.f;
        }
        *(bf16x8*)&Zr[gb] = co;
        z8 = zn; f8 = fn;
    }
}

// ---------------- stats partials (pure stores, no memset/atomics) ----------------
__global__ __launch_bounds__(256) void k_stats(const float* __restrict__ x,
                                               float* __restrict__ stats) {
    __shared__ float ls[4], ls2[4];
    const int sb = blockIdx.x, tid = threadIdx.x;   // sb 0..255
    const int b = sb >> 7;
    const float4* xb = (const float4*)(x + (size_t)b * 64 * 128 * Tt);
    const int n4 = 64 * 128 * Tt / 4;
    float s = 0.f, s2 = 0.f;
    for (int i = (sb & 127) * 256 + tid; i < n4; i += 128 * 256) {
        float4 vv = xb[i];
        s  += vv.x + vv.y + vv.z + vv.w;
        s2 += vv.x * vv.x + vv.y * vv.y + vv.z * vv.z + vv.w * vv.w;
    }
    for (int off = 32; off; off >>= 1) {
        s  += __shfl_down(s, off);
        s2 += __shfl_down(s2, off);
    }
    int lane = tid & 63, w = tid >> 6;
    if (lane == 0) { ls[w] = s; ls2[w] = s2; }
    __syncthreads();
    if (tid == 0) {
        float a = 0.f, a2 = 0.f;
        for (int i = 0; i < 4; i++) { a += ls[i]; a2 += ls2[i]; }
        stats[sb * 2]     = a;
        stats[sb * 2 + 1] = a2;
    }
}

// ---------------- normalize + transpose -> XbT, plus weight packing (grid-stride) ----------
__global__ __launch_bounds__(512) void k_norm(const float* __restrict__ x, const float* __restrict__ stats,
                       const float* __restrict__ gamma, const float* __restrict__ beta,
                       const float* __restrict__ W0, const float* __restrict__ Wr,
                       const float* __restrict__ wct,
                       u16* __restrict__ xbt, u16* __restrict__ W0k,
                       u16* __restrict__ Wrt, u16* __restrict__ Wcto) {
    __shared__ u16 lt[64 * 260];
    __shared__ float sm2[2];
    const int n = blockIdx.x, tid = threadIdx.x;
    const int b = n >> 7, f = n & 127;
    if (tid < 64) {
        float a = 0.f, a2 = 0.f;
        #pragma unroll
        for (int p = 0; p < 2; ++p) {
            int sb = b * 128 + tid + p * 64;
            a  += stats[sb * 2];
            a2 += stats[sb * 2 + 1];
        }
        for (int off = 32; off; off >>= 1) {
            a  += __shfl_down(a, off);
            a2 += __shfl_down(a2, off);
        }
        if (tid == 0) { sm2[0] = a; sm2[1] = a2; }
    }
    // weight packing interleaved before the barrier (independent of lt/sm2 consumers)
    #pragma unroll
    for (int it = 0; it < 2; ++it) {
        int idx = it * 131072 + n * 512 + tid;
        if (idx < 131072) {
            int k = idx >> 14, j = (idx >> 6) & 255, c = idx & 63;
            int d = j >> 7, ck = c * 8 + k;
            W0k[idx] = f2bf(W0[((size_t)d * 512 + ck) * 128 + (j & 127)]);
        } else if (idx < 180224) {
            int r = idx - 131072;
            int i = r & 63, j = (r >> 6) & 255, lidx = r >> 14;
            Wrt[r] = f2bf(Wr[(size_t)(lidx * 2 + (j >> 7)) * 8192 + i * 128 + (j & 127)]);
        } else if (idx < 212992) {
            int r = idx - 180224;
            int o = r >> 9; int k = r & 511; int kk = k >> 6, ci = k & 63;
            Wcto[r] = f2bf(wct[(size_t)ci * 512 + o * 8 + kk]);
        }
    }
    __syncthreads();
    const float inv = 1.0f / (float)(64 * 128 * Tt);
    float mean = sm2[0] * inv;
    float var  = sm2[1] * inv - mean * mean;
    float rstd = rsqrtf(var + EPS_);
    const int c = tid >> 3, vq = tid & 7;
    const float gm = gamma[c] * rstd;
    const float bt = beta[c] - mean * gm;
    const float* xr = x + ((size_t)(b * 64 + c) * 128 + f) * Tt;
    #pragma unroll
    for (int j = 0; j < 16; ++j) {
        int t0 = vq * 2 + j * 16;
        unsigned pv = 0u;
        if (t0 < Tt) {
            float2 xv = *(const float2*)&xr[t0];
            pv = (unsigned)f2bf(fmaf(xv.x, gm, bt)) | ((unsigned)f2bf(fmaf(xv.y, gm, bt)) << 16);
        }
        *(unsigned*)&lt[c * 260 + t0] = pv;
    }
    __syncthreads();
    const int cg = tid & 7, tq = tid >> 3;
    #pragma unroll
    for (int it = 0; it < 4; ++it) {
        int t = it * 64 + tq;
        u16 tmp[8];
        #pragma unroll
        for (int jj = 0; jj < 8; ++jj) tmp[jj] = lt[(cg * 8 + jj) * 260 + t];
        uint4 o;
        o.x = (unsigned)tmp[0] | ((unsigned)tmp[1] << 16);
        o.y = (unsigned)tmp[2] | ((unsigned)tmp[3] << 16);
        o.z = (unsigned)tmp[4] | ((unsigned)tmp[5] << 16);
        o.w = (unsigned)tmp[6] | ((unsigned)tmp[7] << 16);
        *(uint4*)&xbt[(size_t)n * 16384 + t * 64 + cg * 8] = o;
    }
}

// ---------------- mega tail (1024 threads / 16 waves, 8M x 2N wave tiling) ----------------
// LDS map unchanged from R7/R9. Wave (wm = w>>1) owns 32 t-rows; (wn = w&1) owns direction.
#define HS0 0
#define ZT0 19008
#define FT0 34880
#define BM0 50752
#define SH_U16 81856
__global__ __launch_bounds__(1024) void k_tail(const u16* __restrict__ XbT,
                                               const u16* __restrict__ W0k,
                                               const u16* __restrict__ Wrt,
                                               const u16* __restrict__ Wc,
                                               const float* __restrict__ v,
                                               const float* __restrict__ bbias,
                                               const float* __restrict__ bct,
                                               const float* __restrict__ x,
                                               float* __restrict__ out) {
    __shared__ __align__(16) u16 sh[SH_U16];
    u16* Hs = sh + HS0;
    u16* ZT = sh + ZT0;
    u16* FT = sh + FT0;
    u16* Bm = sh + BM0;
    const int tid = threadIdx.x;
    const int n = blockIdx.x;
    const int lane = tid & 63, w = tid >> 6;          // w in 0..15
    const int ml = lane & 15, q = lane >> 4;
    const int wm = w >> 1, wn = w & 1;                // M-tile index / N-half (= direction)
    const int b = n >> 7, f = n & 127;

    for (int lay = 0; lay < 4; ++lay) {
        f32x4 acc[2][8];
        #pragma unroll
        for (int mt = 0; mt < 2; ++mt)
            #pragma unroll
            for (int nt = 0; nt < 8; ++nt) acc[mt][nt] = (f32x4){0.f, 0.f, 0.f, 0.f};

        if (lay == 0) {
            const u16* Xn = XbT + (size_t)n * 16384;
            u16* Bb0 = sh + ZT0;                       // dead ZT/FT span
            u16* Bb1 = Bm;
            dma72g(Xn, 64, Hs, 36, w, lane, 16);       // A tile rows 0..255
            dma72g(W0k, 64, Bb0, 36, w, lane, 16);     // B k=0
            __syncthreads();
            #pragma unroll
            for (int k = 0; k < 8; ++k) {
                u16* Bl = (k & 1) ? Bb1 : Bb0;
                if (k < 7)
                    dma72g(W0k + (size_t)(k + 1) * 16384, 64, (k & 1) ? Bb0 : Bb1, 36, w, lane, 16);
                #pragma unroll
                for (int c2 = 0; c2 < 2; ++c2) {
                    int c0 = c2 * 32;
                    bf16x8 af[2];
                    #pragma unroll
                    for (int mt = 0; mt < 2; ++mt)
                        af[mt] = *(const bf16x8*)&Hs[(wm * 32 + mt * 16 + ml + k) * 72 + c0 + q * 8];
                    #pragma unroll
                    for (int nt = 0; nt < 8; ++nt) {
                        bf16x8 bfr = *(const bf16x8*)&Bl[(wn * 128 + nt * 16 + ml) * 72 + c0 + q * 8];
                        #pragma unroll
                        for (int mt = 0; mt < 2; ++mt)
                            acc[mt][nt] = __builtin_amdgcn_mfma_f32_16x16x32_bf16(af[mt], bfr, acc[mt][nt], 0, 0, 0);
                    }
                }
                __syncthreads();
            }
        } else {
            #pragma unroll
            for (int c2 = 0; c2 < 2; ++c2) {
                int c0 = c2 * 32;
                bf16x8 af[2];
                #pragma unroll
                for (int mt = 0; mt < 2; ++mt)
                    af[mt] = *(const bf16x8*)&Hs[(wm * 32 + mt * 16 + ml + 7) * 72 + c0 + q * 8];
                #pragma unroll
                for (int nt = 0; nt < 8; ++nt) {
                    bf16x8 bfr = *(const bf16x8*)&Bm[(wn * 128 + nt * 16 + ml) * 72 + c0 + q * 8];
                    #pragma unroll
                    for (int mt = 0; mt < 2; ++mt)
                        acc[mt][nt] = __builtin_amdgcn_mfma_f32_16x16x32_bf16(af[mt], bfr, acc[mt][nt], 0, 0, 0);
                }
            }
        }

        // epi: z/f preacts (nt 0..3) -> ZT/FT rows (wn*32+hh); r/x (nt 4..7) stay in registers
        #pragma unroll
        for (int mt = 0; mt < 2; ++mt) {
            int t0 = wm * 32 + mt * 16 + q * 4;
            if (t0 < TnN) {
                bool vec = (t0 + 4 <= TnN);
                #pragma unroll
                for (int nt = 0; nt < 4; ++nt) {
                    int g2 = nt >> 1, hh = (nt & 1) * 16 + ml;
                    u16* P = (g2 ? FT : ZT) + (wn * 32 + hh) * 248;
                    if (vec) {
                        uint2 pv;
                        pv.x = (unsigned)f2bf(acc[mt][nt][0]) | ((unsigned)f2bf(acc[mt][nt][1]) << 16);
                        pv.y = (unsigned)f2bf(acc[mt][nt][2]) | ((unsigned)f2bf(acc[mt][nt][3]) << 16);
                        *(uint2*)&P[t0] = pv;
                    } else {
                        #pragma unroll
                        for (int r = 0; r < 4; ++r) {
                            int t = t0 + r;
                            if (t < TnN) P[t] = f2bf(acc[mt][nt][r]);
                        }
                    }
                }
            }
        }
        __syncthreads();

        // next-B DMA hidden under the serial chain
        if (lay < 3) {
            dma72g(Wrt + (size_t)lay * 16384, 64, Bm, 36, w, lane, 16);
        } else {
            #pragma unroll
            for (int i = 0; i < 4; ++i)
                dma72g(Wc + i * 64, 512, Bm + i * 4608, 9, w, lane, 16);
        }

        const float* vv = v + (size_t)(lay * 2) * 64;
        const float* bv = bbias + (size_t)(lay * 2) * 64;

        if (w < 2 && lane < 32) {
            const int d = w, h = lane;
            const float vf = vv[d * 64 + h], bf_ = bv[d * 64 + h];
            const float kf = -LOG2E * vf;
            u16* Zr = &ZT[(d * 32 + h) * 248];
            u16* Fr = &FT[(d * 32 + h) * 248];
            if (d == 0) chain_run<0>(Zr, Fr, kf, bf_);
            else        chain_run<1>(Zr, Fr, kf, bf_);
        }
        __syncthreads();

        if (lay == 0) {
            for (int i = tid; i < 21 * 72; i += 1024) {
                int r = i / 72, ci = i - r * 72;
                int row = r < 7 ? r : (TnN + r);
                Hs[row * 72 + ci] = 0;
            }
        }
        // h-phase: d2 = wn; r/x preacts from registers, c from ZT; writes Hs
        #pragma unroll
        for (int mt = 0; mt < 2; ++mt) {
            int t0 = wm * 32 + mt * 16 + q * 4;
            #pragma unroll
            for (int hi = 0; hi < 2; ++hi) {
                int hh = hi * 16 + ml;
                float vr_ = vv[wn * 64 + 32 + hh], br_ = bv[wn * 64 + 32 + hh];
                float kr = -LOG2E * vr_;
                const u16* Cr = &ZT[(wn * 32 + hh) * 248];
                f32x4 rp = acc[mt][4 + hi];
                f32x4 xp = acc[mt][6 + hi];
                #pragma unroll
                for (int r = 0; r < 4; ++r) {
                    int t = t0 + r;
                    if (t < TnN) {
                        float ct = bf2f(Cr[t]);
                        float cpr;
                        if (wn == 0) cpr = (t == 0) ? 0.f : bf2f(Cr[t - 1]);
                        else         cpr = (t == TnN - 1) ? 0.f : bf2f(Cr[t + 1]);
                        float xr = fmaf(kr, cpr, -LOG2E * (rp[r] + br_));
                        float rg = __builtin_amdgcn_rcpf(1.f + hw_exp2(xr));
                        float hv = fmaf(rg, ct - xp[r], xp[r]);
                        Hs[(t + 7) * 72 + wn * 32 + hh] = f2bf(hv);
                    }
                }
            }
        }
        __syncthreads();
    }

    // ---- conv phase: unchanged 16-wave M mapping (own accumulators) ----
    {
        u16* T47 = sh + ZT0;
        float* Cf = (float*)(sh + 37440);
        const int tc0 = w * 16 + q * 4;
        f32x4 cacc[4] = {};
        #pragma unroll
        for (int i = 0; i < 4; ++i)
            dma72g(Wc + (4 + i) * 64, 512, T47 + i * 4608, 9, w, lane, 16);
        #pragma unroll
        for (int m = 0; m < 8; ++m) {
            if (m == 4) __syncthreads();
            const u16* Bl = (m < 4) ? (Bm + m * 4608) : (T47 + (m - 4) * 4608);
            #pragma unroll
            for (int c2 = 0; c2 < 2; ++c2) {
                int ci0 = c2 * 32;
                bf16x8 af = *(const bf16x8*)&Hs[(w * 16 + ml - m + 7) * 72 + ci0 + q * 8];
                #pragma unroll
                for (int nt = 0; nt < 4; ++nt) {
                    bf16x8 bfv = *(const bf16x8*)&Bl[(nt * 16 + ml) * 72 + ci0 + q * 8];
                    cacc[nt] = __builtin_amdgcn_mfma_f32_16x16x32_bf16(af, bfv, cacc[nt], 0, 0, 0);
                }
            }
        }
        __syncthreads();
        float bc[4];
        #pragma unroll
        for (int nt = 0; nt < 4; ++nt) bc[nt] = bct[nt * 16 + ml];
        #pragma unroll
        for (int r = 0; r < 4; ++r) {
            int t = tc0 + r;
            if (t < Tt) {
                #pragma unroll
                for (int nt = 0; nt < 4; ++nt)
                    Cf[t * 68 + nt * 16 + ml] = cacc[nt][r] + bc[nt];
            }
        }
        __syncthreads();
        {
            const int sub = tid & 15;
            const int o = tid >> 4;
            const float* xrow = x + ((size_t)(b * 64 + o) * 128 + f) * Tt;
            float* orow = out + ((size_t)(b * 64 + o) * 128 + f) * Tt;
            #pragma unroll
            for (int it = 0; it < 8; ++it) {
                int j = it * 32 + sub * 2;
                if (j < Tt) {
                    float2 xv = *(const float2*)&xrow[j];
                    float2 ov;
                    ov.x = Cf[j * 68 + o] + xv.x;
                    ov.y = Cf[(j + 1) * 68 + o] + xv.y;
                    *(float2*)&orow[j] = ov;
                }
            }
        }
    }
}

extern "C" void kernel_launch(void* const* d_in, const int* in_sizes, int n_in,
                              void* d_out, int out_size, void* d_ws, size_t ws_size,
                              hipStream_t stream) {
    (void)in_sizes; (void)n_in; (void)out_size; (void)ws_size;
    const float* x     = (const float*)d_in[0];
    const float* gamma = (const float*)d_in[1];
    const float* beta  = (const float*)d_in[2];
    const float* W0    = (const float*)d_in[3];
    const float* Wr    = (const float*)d_in[4];
    const float* v     = (const float*)d_in[5];
    const float* bb    = (const float*)d_in[6];
    const float* wct   = (const float*)d_in[7];
    const float* bct   = (const float*)d_in[8];
    float* out = (float*)d_out;

    char* base = (char*)d_ws;
    float* stats = (float*)base;                         // 2048 B: 256 partial (s,s2) pairs
    u16* W0k  = (u16*)(base + 4096);                     // 262144 B  [8 k][256 j][64 c]
    u16* Wrt  = (u16*)(base + 4096 + 262144);            // 98304 B
    u16* Wcto = (u16*)(base + 4096 + 262144 + 98304);    // 65536 B
    u16* XbT  = (u16*)(base + 4096 + 262144 + 98304 + 65536);  // 8.39 MB [256 n][256 t][64 c]

    k_stats<<<dim3(256), 256, 0, stream>>>(x, stats);
    k_norm<<<dim3(256), 512, 0, stream>>>(x, stats, gamma, beta, W0, Wr, wct,
                                          XbT, W0k, Wrt, Wcto);
    k_tail<<<dim3(256), 1024, 0, stream>>>(XbT, W0k, Wrt, Wcto, v, bb, bct, x, out);
}